// Round 1
// 3032.943 us; speedup vs baseline: 1.1383x; 1.1383x over previous
//
#include <hip/hip_runtime.h>
#include <stdint.h>

typedef unsigned short u16;
typedef unsigned int u32;
typedef unsigned long long u64;
typedef __attribute__((ext_vector_type(8))) short bf16x8;
typedef __attribute__((ext_vector_type(4))) float f32x4;
typedef __attribute__((ext_vector_type(4))) u16 u16x4;

#define T_STEPS 256
#define BATCH 64
#define IDIM 1024
#define HDIM 1024
#define NBLK 256
#define NJ 4            // h-columns per block
#define KPAD 2056       // padded K stride (bf16 elems) for LDS W
#define THREADS 512
#define CNT_STRIDE 128  // u32 per barrier (8 slots x 16 u32 = 512 B)
#define NBAR 257
#define GO_OFF 131584                                  // bytes: after cnt (257*512)
#define X_OFF 262144                                   // bytes into ws
#define H_OFF (X_OFF + T_STEPS * BATCH * IDIM * 2)     // bytes into ws
#define LDS_BYTES 83712  // 65792 (W) + 17408 (cand) + 512 (hstage)

static __device__ __forceinline__ u16 f2bf(float f) {
  u32 u = __builtin_bit_cast(u32, f);
  u += 0x7FFFu + ((u >> 16) & 1u);
  return (u16)(u >> 16);
}
static __device__ __forceinline__ float sigf(float x) {
  return __builtin_amdgcn_rcpf(1.f + __expf(-x));
}
static __device__ __forceinline__ float tanhf_(float x) {
  float ax = __builtin_fabsf(x);
  float e = __expf(-2.f * ax);
  float t = 1.f - 2.f * e * __builtin_amdgcn_rcpf(1.f + e);
  return __builtin_copysignf(t, x);
}

// ---- MCS-style grid barrier, now with ACQUIRE-invalidate ----
// Arrive: fire-and-forget atomicAdd on 8 spread lines. Watcher (bid 0, tid<8)
// waits for 32 per line, then writes go[bar]. One poller per block on the
// single-writer go line with s_sleep backoff.
// NEW: h(t) is published with device-scope (sc1) write-through stores, but
// CONSUMED with plain cached loads. Correctness: the pre-arrive __syncthreads
// drains the sc1 h-stores to the IF$ coherence point (vmcnt(0)); after go is
// observed, tid 0 issues an agent-scope acquire fence (buffer_inv sc1) which
// invalidates this CU's L1 and this XCD's L2 so the plain loads re-fetch the
// fresh h lines from IF$ — once per XCD, then L2-shared by its 32 blocks.
// This is the same release/acquire mechanism gbar_heavy already uses.
static __device__ __forceinline__ void gbar(u32* cnt, u32* go, int bar, int bid,
                                            int tid) {
  __syncthreads();  // drains all threads' stores (vmcnt(0) before s_barrier)
  if (tid == 0)
    __hip_atomic_fetch_add(&cnt[bar * CNT_STRIDE + (bid & 7) * 16], 1u,
                           __ATOMIC_RELAXED, __HIP_MEMORY_SCOPE_AGENT);
  if (bid == 0) {
    if (tid < 8) {
      while (__hip_atomic_load(&cnt[bar * CNT_STRIDE + tid * 16],
                               __ATOMIC_RELAXED, __HIP_MEMORY_SCOPE_AGENT) <
             (u32)(NBLK / 8))
        __builtin_amdgcn_s_sleep(1);
    }
    __syncthreads();
    if (tid == 0)
      __hip_atomic_store(&go[bar * 16], 1u, __ATOMIC_RELAXED,
                         __HIP_MEMORY_SCOPE_AGENT);
  } else {
    if (tid == 0) {
      while (__hip_atomic_load(&go[bar * 16], __ATOMIC_RELAXED,
                               __HIP_MEMORY_SCOPE_AGENT) == 0u)
        __builtin_amdgcn_s_sleep(4);
    }
  }
  if (tid == 0)
    __builtin_amdgcn_fence(__ATOMIC_ACQUIRE, "agent");  // buffer_inv sc1
  __syncthreads();
}

// Heavy variant for barrier 0 only: xbf/h0 written with normal (cached)
// stores, so release needs wbl2 and acquire needs inv (threadfence).
static __device__ __forceinline__ void gbar_heavy(u32* cnt, u32* go, int bar,
                                                  int bid, int tid) {
  __syncthreads();
  if (tid == 0) {
    __threadfence();
    __hip_atomic_fetch_add(&cnt[bar * CNT_STRIDE + (bid & 7) * 16], 1u,
                           __ATOMIC_RELAXED, __HIP_MEMORY_SCOPE_AGENT);
  }
  if (bid == 0) {
    if (tid < 8) {
      while (__hip_atomic_load(&cnt[bar * CNT_STRIDE + tid * 16],
                               __ATOMIC_RELAXED, __HIP_MEMORY_SCOPE_AGENT) <
             (u32)(NBLK / 8))
        __builtin_amdgcn_s_sleep(1);
    }
    __syncthreads();
    if (tid == 0)
      __hip_atomic_store(&go[bar * 16], 1u, __ATOMIC_RELAXED,
                         __HIP_MEMORY_SCOPE_AGENT);
  } else {
    if (tid == 0) {
      while (__hip_atomic_load(&go[bar * 16], __ATOMIC_RELAXED,
                               __HIP_MEMORY_SCOPE_AGENT) == 0u)
        __builtin_amdgcn_s_sleep(4);
    }
  }
  if (tid == 0) __threadfence();  // acquire: invalidate L1/L2 before reads
  __syncthreads();
}

__global__ __launch_bounds__(THREADS, 2)
void lstm_persistent(const float* __restrict__ x, const float* __restrict__ h0,
                     const float* __restrict__ c0, const float* __restrict__ W,
                     const float* __restrict__ bias, const int* __restrict__ L,
                     float* __restrict__ out, u16* __restrict__ xbf,
                     u16* __restrict__ hbuf, u32* __restrict__ cnt,
                     u32* __restrict__ go) {
  extern __shared__ char smem[];
  u16* Wlds = (u16*)smem;                 // [16 cols][KPAD] bf16 = 65792 B
  float* cand = (float*)(smem + 65792);   // [4 kq][64 b][17] f32 = 17408 B
  u16* hstage = (u16*)(smem + 83200);     // [256] bf16 staging = 512 B

  const int bid = blockIdx.x;
  const int tid = threadIdx.x;
  const int wave = tid >> 6;
  const int lane = tid & 63;
  const int q = lane >> 4;   // quad 0..3
  const int ln = lane & 15;
  const int mh = wave & 1;   // M half: rows [32*mh, 32*mh+32)
  const int kh = wave >> 1;  // K quarter: k in [kh*512, kh*512+512)

  // ---- phase 0a: x -> bf16 (grid-wide), h0 -> bf16 into hbuf[1] ----
  {
    const int gtid = bid * THREADS + tid;
    const f32x4* xv = (const f32x4*)x;
    u16x4* ov = (u16x4*)xbf;
#pragma unroll
    for (int it = 0; it < 32; ++it) {
      int i = gtid + it * (NBLK * THREADS);
      f32x4 v = xv[i];
      u16x4 o;
      o[0] = f2bf(v[0]); o[1] = f2bf(v[1]); o[2] = f2bf(v[2]); o[3] = f2bf(v[3]);
      ov[i] = o;
    }
    if (gtid < BATCH * HDIM) hbuf[BATCH * HDIM + gtid] = f2bf(h0[gtid]);
  }

  // ---- phase 0b: W slice -> LDS (bf16, column-major with K pad) ----
  {
    const int g = tid & 3;
    const int kq2 = tid >> 2;  // 0..127
    const f32x4* Wv = (const f32x4*)W;  // one W row = 1024 f32x4
#pragma unroll 4
    for (int i = 0; i < 16; ++i) {
      int k = kq2 + 128 * i;
      f32x4 w4 = Wv[(size_t)k * 1024 + g * 256 + bid];
#pragma unroll
      for (int jj = 0; jj < 4; ++jj)
        Wlds[(g * 4 + jj) * KPAD + k] = f2bf(w4[jj]);
    }
  }

  // ---- per-thread pointwise state (threads 0..255: (b, j) pairs) ----
  float c_reg = 0.f, h_reg = 0.f, b_i = 0.f, b_f = 0.f, b_o = 0.f, b_g = 0.f;
  int Lb = 0, pb = 0, pj = 0;
  if (tid < 256) {
    pb = tid >> 2;
    pj = tid & 3;
    int gj = bid * NJ + pj;
    Lb = L[pb];
    c_reg = c0[pb * HDIM + gj];
    h_reg = h0[pb * HDIM + gj];
    b_i = bias[0 * HDIM + gj];
    b_f = bias[1 * HDIM + gj];
    b_o = bias[2 * HDIM + gj];
    b_g = bias[3 * HDIM + gj];
  }

  gbar_heavy(cnt, go, 0, bid, tid);  // x/h0 conversion visible everywhere

  const int arow = 32 * mh + ln;        // batch row of this wave's tile0
  const bool fromx = (kh < 2);
  const int kbase = (kh & 1) * 512;     // k offset within source (x or h)
  const u16* wp = &Wlds[ln * KPAD + kh * 512 + q * 8];

  for (int t = 0; t < T_STEPS; ++t) {
    f32x4 acc0 = {0.f, 0.f, 0.f, 0.f};
    f32x4 acc1 = {0.f, 0.f, 0.f, 0.f};
    // Unified path: plain cached vector loads for BOTH x and h halves.
    // x: immutable, L2-hot. h: fresh-by-construction after the barrier's
    // acquire-invalidate — first touch per XCD misses to IF$ (where the sc1
    // publish stores landed), then L2-shared by the XCD's 32 blocks.
    const u16* base = fromx
        ? (xbf + (size_t)t * (BATCH * IDIM))
        : (hbuf + ((t + 1) & 1) * (BATCH * HDIM));
    const u16* pa0 = base + arow * 1024 + kbase + q * 8;
    const u16* pa1 = pa0 + 16 * 1024;
#pragma unroll
    for (int ks = 0; ks < 16; ++ks) {
      bf16x8 a0 = *(const bf16x8*)(pa0 + ks * 32);
      bf16x8 a1 = *(const bf16x8*)(pa1 + ks * 32);
      bf16x8 bw = *(const bf16x8*)(wp + ks * 32);
      acc0 = __builtin_amdgcn_mfma_f32_16x16x32_bf16(a0, bw, acc0, 0, 0, 0);
      acc1 = __builtin_amdgcn_mfma_f32_16x16x32_bf16(a1, bw, acc1, 0, 0, 0);
    }
    // C/D layout: col = lane&15, row-in-tile = quad*4 + reg  (m89-verified)
    {
      float* c0p = &cand[(kh * 64 + 32 * mh + q * 4) * 17 + ln];
      float* c1p = c0p + 16 * 17;
#pragma unroll
      for (int r = 0; r < 4; ++r) {
        c0p[r * 17] = acc0[r];
        c1p[r * 17] = acc1[r];
      }
    }
    __syncthreads();
    if (tid < 256) {
      float vi = b_i, vf = b_f, vo = b_o, vg = b_g;
#pragma unroll
      for (int p = 0; p < 4; ++p) {
        const float* cp = &cand[(p * 64 + pb) * 17];
        vi += cp[pj];
        vf += cp[4 + pj];
        vo += cp[8 + pj];
        vg += cp[12 + pj];
      }
      float ig = sigf(vi), fg = sigf(vf), og = sigf(vo), gg = tanhf_(vg);
      float cn = ig * gg + fg * c_reg;
      float hn = og * tanhf_(cn);
      if (t < Lb) { c_reg = cn; h_reg = hn; }  // freeze past sequence end
      out[((size_t)t * BATCH + pb) * HDIM + bid * NJ + pj] = h_reg;
      hstage[tid] = f2bf(h_reg);
    }
    __syncthreads();
    if (tid < 64) {
      // publish h: device-scope u64 stores (4 bf16 each), write-through to IF$
      u64 v = ((const u64*)hstage)[tid];
      u64* dst = (u64*)(hbuf + (t & 1) * (BATCH * HDIM) + tid * HDIM + bid * NJ);
      __hip_atomic_store(dst, v, __ATOMIC_RELAXED, __HIP_MEMORY_SCOPE_AGENT);
    }
    gbar(cnt, go, 1 + t, bid, tid);  // h(t) at IF$ before add (vmcnt drain)
  }
}

extern "C" void kernel_launch(void* const* d_in, const int* in_sizes, int n_in,
                              void* d_out, int out_size, void* d_ws, size_t ws_size,
                              hipStream_t stream) {
  (void)in_sizes; (void)n_in; (void)out_size; (void)ws_size;
  const float* x = (const float*)d_in[0];
  const float* h0 = (const float*)d_in[1];
  const float* c0 = (const float*)d_in[2];
  const float* W = (const float*)d_in[3];
  const float* bias = (const float*)d_in[4];
  const int* L = (const int*)d_in[5];
  float* out = (float*)d_out;

  char* ws = (char*)d_ws;
  u32* cnt = (u32*)ws;
  u32* go = (u32*)(ws + GO_OFF);
  u16* xbf = (u16*)(ws + X_OFF);
  u16* hbuf = (u16*)(ws + H_OFF);

  hipFuncSetAttribute(reinterpret_cast<const void*>(lstm_persistent),
                      hipFuncAttributeMaxDynamicSharedMemorySize, 160 * 1024);
  hipMemsetAsync(ws, 0, X_OFF, stream);  // zero cnt + go
  hipLaunchKernelGGL(lstm_persistent, dim3(NBLK), dim3(THREADS), LDS_BYTES,
                     stream, x, h0, c0, W, bias, L, out, xbf, hbuf, cnt, go);
}

// Round 4
// 2968.584 us; speedup vs baseline: 1.1629x; 1.0217x over previous
//
#include <hip/hip_runtime.h>
#include <stdint.h>

typedef unsigned short u16;
typedef unsigned int u32;
typedef unsigned long long u64;
typedef __attribute__((ext_vector_type(8))) short bf16x8;
typedef __attribute__((ext_vector_type(4))) float f32x4;
typedef __attribute__((ext_vector_type(4))) u16 u16x4;

#define T_STEPS 256
#define BATCH 64
#define IDIM 1024
#define HDIM 1024
#define NBLK 256
#define NJ 4            // h-columns per block
#define KPAD 2056       // padded K stride (bf16 elems) for LDS W
#define THREADS 512
// Epoch barrier: ONE 64B line per block (arrive) + ONE go line (release).
// 256*64B + 64B, all inside the round-1 ws prefix; total ws footprint
// byte-identical to the known-good round-1 kernel.
#define FLAG_LINE_U32 16                       // 64 B spacing
#define GO_U32 (NBLK * FLAG_LINE_U32)          // go line right after flags
#define X_OFF 262144                           // bytes into ws (same as round 1)
#define H_OFF (X_OFF + T_STEPS * BATCH * IDIM * 2)  // bytes into ws
#define LDS_BYTES 83712  // 65792 (W) + 17408 (cand) + 512 (hstage)

static __device__ __forceinline__ u16 f2bf(float f) {
  u32 u = __builtin_bit_cast(u32, f);
  u += 0x7FFFu + ((u >> 16) & 1u);
  return (u16)(u >> 16);
}
static __device__ __forceinline__ float sigf(float x) {
  return __builtin_amdgcn_rcpf(1.f + __expf(-x));
}
static __device__ __forceinline__ float tanhf_(float x) {
  float ax = __builtin_fabsf(x);
  float e = __expf(-2.f * ax);
  float t = 1.f - 2.f * e * __builtin_amdgcn_rcpf(1.f + e);
  return __builtin_copysignf(t, x);
}

// ---- store-arrive / watcher-release epoch barrier ----
// History: round-1 (worked, 3033us) used 32-deep atomicAdd chains to arrive
// (serialized RMWs at the IF$ coherence point, ~3-6us/step). Rounds 2-3
// (hung) replaced the wait with all-to-all polling: 65K concurrent scattered
// sc1 poll loads congested the coherence fabric. This version keeps the best
// half of each:
//   arrive : each block's tid0 does ONE relaxed sc1 STORE of epoch E to its
//            own 64B line -- no RMW, no same-line contention, 256 stores
//            land in parallel.
//   watch  : ONLY block 0 polls -- threads 0..255 poll one line each (256
//            pollers grid-wide, 256x less poll traffic than rounds 2-3),
//            then tid0 publishes E to the single go line.
//   release: every other block has ONE poller on go (the exact pattern that
//            ran fine in rounds 0-1), s_sleep backoff.
// Monotonic epochs make slot reuse safe (a block is at most one barrier
// ahead; observing >=E implies E arrived) -- no reset, no per-barrier slots.
// Ordering unchanged from the verified round-1 mechanism: the entry
// __syncthreads drains this block's sc1 h-stores to the IF$ coherence point
// before the flag store issues; after release, tid0 issues the agent acquire
// fence (buffer_inv sc1) so plain cached loads re-fetch fresh h lines from
// IF$ (once per XCD, then L2-shared). heavy=true (barrier 0 only) adds
// threadfence write-back/invalidate because xbf/h0 used normal cached stores.
static __device__ __forceinline__ void gbar(u32* flags, u32* go, u32 epoch,
                                            int bid, int tid, bool heavy) {
  __syncthreads();  // drains all threads' stores (vmcnt(0) before s_barrier)
  if (tid == 0) {
    if (heavy) __threadfence();  // release: wbl2 so cached xbf writes visible
    __hip_atomic_store(&flags[bid * FLAG_LINE_U32], epoch, __ATOMIC_RELAXED,
                       __HIP_MEMORY_SCOPE_AGENT);
  }
  if (bid == 0) {
    if (tid < NBLK) {
      while (__hip_atomic_load(&flags[tid * FLAG_LINE_U32], __ATOMIC_RELAXED,
                               __HIP_MEMORY_SCOPE_AGENT) < epoch)
        __builtin_amdgcn_s_sleep(1);
    }
    __syncthreads();
    if (tid == 0)
      __hip_atomic_store(go, epoch, __ATOMIC_RELAXED,
                         __HIP_MEMORY_SCOPE_AGENT);
  } else {
    if (tid == 0) {
      while (__hip_atomic_load(go, __ATOMIC_RELAXED,
                               __HIP_MEMORY_SCOPE_AGENT) < epoch)
        __builtin_amdgcn_s_sleep(2);
    }
  }
  if (tid == 0) {
    if (heavy)
      __threadfence();  // acquire: invalidate L1/L2 before reads
    else
      __builtin_amdgcn_fence(__ATOMIC_ACQUIRE, "agent");  // buffer_inv sc1
  }
  __syncthreads();
}

__global__ __launch_bounds__(THREADS, 2)
void lstm_persistent(const float* __restrict__ x, const float* __restrict__ h0,
                     const float* __restrict__ c0, const float* __restrict__ W,
                     const float* __restrict__ bias, const int* __restrict__ L,
                     float* __restrict__ out, u16* __restrict__ xbf,
                     u16* __restrict__ hbuf, u32* __restrict__ flags) {
  extern __shared__ char smem[];
  u16* Wlds = (u16*)smem;                 // [16 cols][KPAD] bf16 = 65792 B
  float* cand = (float*)(smem + 65792);   // [4 kq][64 b][17] f32 = 17408 B
  u16* hstage = (u16*)(smem + 83200);     // [256] bf16 staging = 512 B

  u32* go = flags + GO_U32;

  const int bid = blockIdx.x;
  const int tid = threadIdx.x;
  const int wave = tid >> 6;
  const int lane = tid & 63;
  const int q = lane >> 4;   // quad 0..3
  const int ln = lane & 15;
  const int mh = wave & 1;   // M half: rows [32*mh, 32*mh+32)
  const int kh = wave >> 1;  // K quarter: k in [kh*512, kh*512+512)

  // ---- phase 0a: x -> bf16 (grid-wide), h0 -> bf16 into hbuf[1] ----
  {
    const int gtid = bid * THREADS + tid;
    const f32x4* xv = (const f32x4*)x;
    u16x4* ov = (u16x4*)xbf;
#pragma unroll
    for (int it = 0; it < 32; ++it) {
      int i = gtid + it * (NBLK * THREADS);
      f32x4 v = xv[i];
      u16x4 o;
      o[0] = f2bf(v[0]); o[1] = f2bf(v[1]); o[2] = f2bf(v[2]); o[3] = f2bf(v[3]);
      ov[i] = o;
    }
    if (gtid < BATCH * HDIM) hbuf[BATCH * HDIM + gtid] = f2bf(h0[gtid]);
  }

  // ---- phase 0b: W slice -> LDS (bf16, column-major with K pad) ----
  {
    const int g = tid & 3;
    const int kq2 = tid >> 2;  // 0..127
    const f32x4* Wv = (const f32x4*)W;  // one W row = 1024 f32x4
#pragma unroll 4
    for (int i = 0; i < 16; ++i) {
      int k = kq2 + 128 * i;
      f32x4 w4 = Wv[(size_t)k * 1024 + g * 256 + bid];
#pragma unroll
      for (int jj = 0; jj < 4; ++jj)
        Wlds[(g * 4 + jj) * KPAD + k] = f2bf(w4[jj]);
    }
  }

  // ---- per-thread pointwise state (threads 0..255: (b, j) pairs) ----
  float c_reg = 0.f, h_reg = 0.f, b_i = 0.f, b_f = 0.f, b_o = 0.f, b_g = 0.f;
  int Lb = 0, pb = 0, pj = 0;
  if (tid < 256) {
    pb = tid >> 2;
    pj = tid & 3;
    int gj = bid * NJ + pj;
    Lb = L[pb];
    c_reg = c0[pb * HDIM + gj];
    h_reg = h0[pb * HDIM + gj];
    b_i = bias[0 * HDIM + gj];
    b_f = bias[1 * HDIM + gj];
    b_o = bias[2 * HDIM + gj];
    b_g = bias[3 * HDIM + gj];
  }

  gbar(flags, go, 1, bid, tid, /*heavy=*/true);  // x/h0 visible everywhere

  const int arow = 32 * mh + ln;        // batch row of this wave's tile0
  const bool fromx = (kh < 2);
  const int kbase = (kh & 1) * 512;     // k offset within source (x or h)
  const u16* wp = &Wlds[ln * KPAD + kh * 512 + q * 8];

  for (int t = 0; t < T_STEPS; ++t) {
    f32x4 acc0 = {0.f, 0.f, 0.f, 0.f};
    f32x4 acc1 = {0.f, 0.f, 0.f, 0.f};
    // Unified path: plain cached vector loads for BOTH x and h halves.
    // x: immutable, L2-hot (refetched from IF$ after each barrier's inv).
    // h: fresh-by-construction after the barrier's acquire-invalidate --
    // first touch per XCD misses to IF$ (where the sc1 publish stores
    // landed), then L2-shared by the XCD's 32 blocks.
    const u16* base = fromx
        ? (xbf + (size_t)t * (BATCH * IDIM))
        : (hbuf + ((t + 1) & 1) * (BATCH * HDIM));
    const u16* pa0 = base + arow * 1024 + kbase + q * 8;
    const u16* pa1 = pa0 + 16 * 1024;
#pragma unroll
    for (int ks = 0; ks < 16; ++ks) {
      bf16x8 a0 = *(const bf16x8*)(pa0 + ks * 32);
      bf16x8 a1 = *(const bf16x8*)(pa1 + ks * 32);
      bf16x8 bw = *(const bf16x8*)(wp + ks * 32);
      acc0 = __builtin_amdgcn_mfma_f32_16x16x32_bf16(a0, bw, acc0, 0, 0, 0);
      acc1 = __builtin_amdgcn_mfma_f32_16x16x32_bf16(a1, bw, acc1, 0, 0, 0);
    }
    // C/D layout: col = lane&15, row-in-tile = quad*4 + reg  (m89-verified)
    {
      float* c0p = &cand[(kh * 64 + 32 * mh + q * 4) * 17 + ln];
      float* c1p = c0p + 16 * 17;
#pragma unroll
      for (int r = 0; r < 4; ++r) {
        c0p[r * 17] = acc0[r];
        c1p[r * 17] = acc1[r];
      }
    }
    __syncthreads();
    if (tid < 256) {
      float vi = b_i, vf = b_f, vo = b_o, vg = b_g;
#pragma unroll
      for (int p = 0; p < 4; ++p) {
        const float* cp = &cand[(p * 64 + pb) * 17];
        vi += cp[pj];
        vf += cp[4 + pj];
        vo += cp[8 + pj];
        vg += cp[12 + pj];
      }
      float ig = sigf(vi), fg = sigf(vf), og = sigf(vo), gg = tanhf_(vg);
      float cn = ig * gg + fg * c_reg;
      float hn = og * tanhf_(cn);
      if (t < Lb) { c_reg = cn; h_reg = hn; }  // freeze past sequence end
      out[((size_t)t * BATCH + pb) * HDIM + bid * NJ + pj] = h_reg;
      hstage[tid] = f2bf(h_reg);
    }
    if (t == T_STEPS - 1) break;  // h(255) has no consumer: skip publish+barrier
    __syncthreads();
    if (tid < 64) {
      // publish h: device-scope u64 stores (4 bf16 each), write-through to IF$
      u64 v = ((const u64*)hstage)[tid];
      u64* dst = (u64*)(hbuf + (t & 1) * (BATCH * HDIM) + tid * HDIM + bid * NJ);
      __hip_atomic_store(dst, v, __ATOMIC_RELAXED, __HIP_MEMORY_SCOPE_AGENT);
    }
    gbar(flags, go, (u32)(t + 2), bid, tid, /*heavy=*/false);  // h(t) at IF$
  }
}

extern "C" void kernel_launch(void* const* d_in, const int* in_sizes, int n_in,
                              void* d_out, int out_size, void* d_ws, size_t ws_size,
                              hipStream_t stream) {
  (void)in_sizes; (void)n_in; (void)out_size; (void)ws_size;
  const float* x = (const float*)d_in[0];
  const float* h0 = (const float*)d_in[1];
  const float* c0 = (const float*)d_in[2];
  const float* W = (const float*)d_in[3];
  const float* bias = (const float*)d_in[4];
  const int* L = (const int*)d_in[5];
  float* out = (float*)d_out;

  char* ws = (char*)d_ws;
  u32* flags = (u32*)ws;
  u16* xbf = (u16*)(ws + X_OFF);
  u16* hbuf = (u16*)(ws + H_OFF);

  hipFuncSetAttribute(reinterpret_cast<const void*>(lstm_persistent),
                      hipFuncAttributeMaxDynamicSharedMemorySize, 160 * 1024);
  hipMemsetAsync(ws, 0, 32768, stream);  // zero epoch flags + go line
  hipLaunchKernelGGL(lstm_persistent, dim3(NBLK), dim3(THREADS), LDS_BYTES,
                     stream, x, h0, c0, W, bias, L, out, xbf, hbuf, flags);
}

// Round 5
// 2612.474 us; speedup vs baseline: 1.3215x; 1.1363x over previous
//
#include <hip/hip_runtime.h>
#include <stdint.h>

typedef unsigned short u16;
typedef unsigned int u32;
typedef unsigned long long u64;
typedef __attribute__((ext_vector_type(8))) short bf16x8;
typedef __attribute__((ext_vector_type(4))) float f32x4;
typedef __attribute__((ext_vector_type(4))) u16 u16x4;

#define T_STEPS 256
#define BATCH 64
#define IDIM 1024
#define HDIM 1024
#define NBLK 256
#define NJ 4            // h-columns per block
#define KPAD 2056       // padded K stride (bf16 elems) for LDS W
#define THREADS 512
// Epoch barrier: 256 arrive lines (64B each) + 8 go lines (one per bid&7).
#define FLAG_LINE_U32 16                       // 64 B spacing
#define GO_U32 (NBLK * FLAG_LINE_U32)          // go lines after arrive flags
#define X_OFF 262144                           // bytes into ws (same as round 4)
#define H_OFF (X_OFF + T_STEPS * BATCH * IDIM * 2)  // bytes into ws
#define LDS_BYTES 83712  // 65792 (W) + 17408 (cand) + 512 (hstage)

static __device__ __forceinline__ u16 f2bf(float f) {
  u32 u = __builtin_bit_cast(u32, f);
  u += 0x7FFFu + ((u >> 16) & 1u);
  return (u16)(u >> 16);
}
static __device__ __forceinline__ float sigf(float x) {
  return __builtin_amdgcn_rcpf(1.f + __expf(-x));
}
static __device__ __forceinline__ float tanhf_(float x) {
  float ax = __builtin_fabsf(x);
  float e = __expf(-2.f * ax);
  float t = 1.f - 2.f * e * __builtin_amdgcn_rcpf(1.f + e);
  return __builtin_copysignf(t, x);
}

// ---- split-phase epoch barrier ----
// Rounds 0/1/4 falsified "h-path" and "arrive-RMW" theories (3 barrier
// structures within 0.5us/step of each other). New theory: the pre-arrive
// vmcnt(0) drain was waiting on CACHED out-stores stuck in a 4-XCD RFO
// ping-pong (each 64B out line is written 16B-each by 4 blocks on 4 XCDs;
// FETCH/WRITE ~4x out size corroborates). This version: (a) out becomes sc1
// write-through issued AFTER the arrive (off-chain, no RFO); (b) the barrier
// is split into arrive (end of step t) and wait (in step t+1, AFTER the
// h-independent x-half compute) so x-fetch hides under propagation; (c)
// release is wave-parallel: block 0's wave 7 (an h-wave, no pre-wait work)
// polls all 256 flags (4 per lane, __all exit) and stores 8 per-(bid&7) go
// lines; each other block has ONE poller (tid 448, also an h-wave lane).
// Ordering mechanism unchanged from verified rounds 1/4: sc1 h-publish ->
// __syncthreads vmcnt-drain -> arrive store; observe -> agent acquire fence
// (buffer_inv sc1) -> cached h loads refetch from IF$ (once per XCD).
static __device__ __forceinline__ void gwait(u32* flags, u32* go, u32 e,
                                             int bid, int tid, int lane) {
  if (bid == 0) {
    if ((tid >> 6) == 7) {  // wave 7: wave-parallel watcher
      const u32* p0 = &flags[lane * FLAG_LINE_U32];
      const u32* p1 = &flags[(lane + 64) * FLAG_LINE_U32];
      const u32* p2 = &flags[(lane + 128) * FLAG_LINE_U32];
      const u32* p3 = &flags[(lane + 192) * FLAG_LINE_U32];
      while (true) {
        u32 a = __hip_atomic_load(p0, __ATOMIC_RELAXED, __HIP_MEMORY_SCOPE_AGENT);
        u32 b = __hip_atomic_load(p1, __ATOMIC_RELAXED, __HIP_MEMORY_SCOPE_AGENT);
        u32 c = __hip_atomic_load(p2, __ATOMIC_RELAXED, __HIP_MEMORY_SCOPE_AGENT);
        u32 d = __hip_atomic_load(p3, __ATOMIC_RELAXED, __HIP_MEMORY_SCOPE_AGENT);
        int mine = (a >= e) && (b >= e) && (c >= e) && (d >= e);
        if (__all(mine)) break;
        __builtin_amdgcn_s_sleep(1);
      }
      if (lane < 8)
        __hip_atomic_store(&go[lane * FLAG_LINE_U32], e, __ATOMIC_RELAXED,
                           __HIP_MEMORY_SCOPE_AGENT);
    }
  } else {
    if (tid == 448) {  // lane 0 of wave 7: no pre-wait work, polls instantly
      while (__hip_atomic_load(&go[(bid & 7) * FLAG_LINE_U32], __ATOMIC_RELAXED,
                               __HIP_MEMORY_SCOPE_AGENT) < e)
        __builtin_amdgcn_s_sleep(2);
    }
  }
  if (tid == 448)
    __builtin_amdgcn_fence(__ATOMIC_ACQUIRE, "agent");  // buffer_inv sc1
  __syncthreads();
}

// Heavy full barrier for epoch 1 only (xbf/h0 written with cached stores).
static __device__ __forceinline__ void gbar_heavy(u32* flags, u32* go, int bid,
                                                  int tid) {
  __syncthreads();
  if (tid == 0) {
    __threadfence();  // release: wbl2 so cached xbf writes visible
    __hip_atomic_store(&flags[bid * FLAG_LINE_U32], 1u, __ATOMIC_RELAXED,
                       __HIP_MEMORY_SCOPE_AGENT);
  }
  if (bid == 0) {
    if (tid < NBLK) {
      while (__hip_atomic_load(&flags[tid * FLAG_LINE_U32], __ATOMIC_RELAXED,
                               __HIP_MEMORY_SCOPE_AGENT) < 1u)
        __builtin_amdgcn_s_sleep(1);
    }
    __syncthreads();
    if (tid < 8)
      __hip_atomic_store(&go[tid * FLAG_LINE_U32], 1u, __ATOMIC_RELAXED,
                         __HIP_MEMORY_SCOPE_AGENT);
  } else {
    if (tid == 0) {
      while (__hip_atomic_load(&go[(bid & 7) * FLAG_LINE_U32], __ATOMIC_RELAXED,
                               __HIP_MEMORY_SCOPE_AGENT) < 1u)
        __builtin_amdgcn_s_sleep(2);
    }
  }
  if (tid == 0) __threadfence();  // acquire: invalidate L1/L2 before reads
  __syncthreads();
}

__global__ __launch_bounds__(THREADS, 2)
void lstm_persistent(const float* __restrict__ x, const float* __restrict__ h0,
                     const float* __restrict__ c0, const float* __restrict__ W,
                     const float* __restrict__ bias, const int* __restrict__ L,
                     float* __restrict__ out, u16* __restrict__ xbf,
                     u16* __restrict__ hbuf, u32* __restrict__ flags) {
  extern __shared__ char smem[];
  u16* Wlds = (u16*)smem;                 // [16 cols][KPAD] bf16 = 65792 B
  float* cand = (float*)(smem + 65792);   // [4 kq][64 b][17] f32 = 17408 B
  u16* hstage = (u16*)(smem + 83200);     // [256] bf16 staging = 512 B

  u32* go = flags + GO_U32;

  const int bid = blockIdx.x;
  const int tid = threadIdx.x;
  const int wave = tid >> 6;
  const int lane = tid & 63;
  const int q = lane >> 4;   // quad 0..3
  const int ln = lane & 15;
  const int mh = wave & 1;   // M half: rows [32*mh, 32*mh+32)
  const int kh = wave >> 1;  // K quarter: k in [kh*512, kh*512+512)

  // ---- phase 0a: x -> bf16 (grid-wide), h0 -> bf16 into hbuf[1] ----
  {
    const int gtid = bid * THREADS + tid;
    const f32x4* xv = (const f32x4*)x;
    u16x4* ov = (u16x4*)xbf;
#pragma unroll
    for (int it = 0; it < 32; ++it) {
      int i = gtid + it * (NBLK * THREADS);
      f32x4 v = xv[i];
      u16x4 o;
      o[0] = f2bf(v[0]); o[1] = f2bf(v[1]); o[2] = f2bf(v[2]); o[3] = f2bf(v[3]);
      ov[i] = o;
    }
    if (gtid < BATCH * HDIM) hbuf[BATCH * HDIM + gtid] = f2bf(h0[gtid]);
  }

  // ---- phase 0b: W slice -> LDS (bf16, column-major with K pad) ----
  {
    const int g = tid & 3;
    const int kq2 = tid >> 2;  // 0..127
    const f32x4* Wv = (const f32x4*)W;  // one W row = 1024 f32x4
#pragma unroll 4
    for (int i = 0; i < 16; ++i) {
      int k = kq2 + 128 * i;
      f32x4 w4 = Wv[(size_t)k * 1024 + g * 256 + bid];
#pragma unroll
      for (int jj = 0; jj < 4; ++jj)
        Wlds[(g * 4 + jj) * KPAD + k] = f2bf(w4[jj]);
    }
  }

  // ---- per-thread pointwise state (threads 0..255: (b, j) pairs) ----
  float c_reg = 0.f, h_reg = 0.f, b_i = 0.f, b_f = 0.f, b_o = 0.f, b_g = 0.f;
  int Lb = 0, pb = 0, pj = 0;
  if (tid < 256) {
    pb = tid >> 2;
    pj = tid & 3;
    int gj = bid * NJ + pj;
    Lb = L[pb];
    c_reg = c0[pb * HDIM + gj];
    h_reg = h0[pb * HDIM + gj];
    b_i = bias[0 * HDIM + gj];
    b_f = bias[1 * HDIM + gj];
    b_o = bias[2 * HDIM + gj];
    b_g = bias[3 * HDIM + gj];
  }

  gbar_heavy(flags, go, bid, tid);  // epoch 1: x/h0 visible everywhere

  const int arow = 32 * mh + ln;        // batch row of this wave's tile0
  const bool fromx = (kh < 2);
  const int kbase = (kh & 1) * 512;     // k offset within source (x or h)
  const u16* wp = &Wlds[ln * KPAD + kh * 512 + q * 8];

  for (int t = 0; t < T_STEPS; ++t) {
    f32x4 acc0 = {0.f, 0.f, 0.f, 0.f};
    f32x4 acc1 = {0.f, 0.f, 0.f, 0.f};
    // ---- x-phase (h-independent): runs BEFORE the wait, hides under the
    // barrier propagation. Waves 0-3 only; h-waves fall through to gwait.
    if (fromx) {
      const u16* pa0 =
          xbf + (size_t)t * (BATCH * IDIM) + arow * 1024 + kbase + q * 8;
      const u16* pa1 = pa0 + 16 * 1024;
#pragma unroll
      for (int ks = 0; ks < 16; ++ks) {
        bf16x8 a0 = *(const bf16x8*)(pa0 + ks * 32);
        bf16x8 a1 = *(const bf16x8*)(pa1 + ks * 32);
        bf16x8 bw = *(const bf16x8*)(wp + ks * 32);
        acc0 = __builtin_amdgcn_mfma_f32_16x16x32_bf16(a0, bw, acc0, 0, 0, 0);
        acc1 = __builtin_amdgcn_mfma_f32_16x16x32_bf16(a1, bw, acc1, 0, 0, 0);
      }
    }
    // Pin: x-MFMAs must not sink past the wait (keep-alive read + sched pin).
    asm volatile("" ::"v"(acc0), "v"(acc1));
    __builtin_amdgcn_sched_barrier(0);

    // ---- wait for h(t-1) published (epoch t+1); t=0 covered by heavy bar.
    if (t > 0) gwait(flags, go, (u32)(t + 1), bid, tid, lane);

    // ---- h-phase: plain cached loads, fresh after the acquire-invalidate.
    if (!fromx) {
      const u16* pa0 = hbuf + ((t + 1) & 1) * (BATCH * HDIM) + arow * 1024 +
                       kbase + q * 8;
      const u16* pa1 = pa0 + 16 * 1024;
#pragma unroll
      for (int ks = 0; ks < 16; ++ks) {
        bf16x8 a0 = *(const bf16x8*)(pa0 + ks * 32);
        bf16x8 a1 = *(const bf16x8*)(pa1 + ks * 32);
        bf16x8 bw = *(const bf16x8*)(wp + ks * 32);
        acc0 = __builtin_amdgcn_mfma_f32_16x16x32_bf16(a0, bw, acc0, 0, 0, 0);
        acc1 = __builtin_amdgcn_mfma_f32_16x16x32_bf16(a1, bw, acc1, 0, 0, 0);
      }
    }
    // C/D layout: col = lane&15, row-in-tile = quad*4 + reg  (m89-verified)
    {
      float* c0p = &cand[(kh * 64 + 32 * mh + q * 4) * 17 + ln];
      float* c1p = c0p + 16 * 17;
#pragma unroll
      for (int r = 0; r < 4; ++r) {
        c0p[r * 17] = acc0[r];
        c1p[r * 17] = acc1[r];
      }
    }
    __syncthreads();
    if (tid < 256) {
      float vi = b_i, vf = b_f, vo = b_o, vg = b_g;
#pragma unroll
      for (int p = 0; p < 4; ++p) {
        const float* cp = &cand[(p * 64 + pb) * 17];
        vi += cp[pj];
        vf += cp[4 + pj];
        vo += cp[8 + pj];
        vg += cp[12 + pj];
      }
      float ig = sigf(vi), fg = sigf(vf), og = sigf(vo), gg = tanhf_(vg);
      float cn = ig * gg + fg * c_reg;
      float hn = og * tanhf_(cn);
      if (t < Lb) { c_reg = cn; h_reg = hn; }  // freeze past sequence end
      hstage[tid] = f2bf(h_reg);
    }
    __syncthreads();
    if (t < T_STEPS - 1) {
      if (tid < 64) {
        // publish h: device-scope u64 stores (4 bf16), write-through to IF$
        u64 v = ((const u64*)hstage)[tid];
        u64* dst =
            (u64*)(hbuf + (t & 1) * (BATCH * HDIM) + tid * HDIM + bid * NJ);
        __hip_atomic_store(dst, v, __ATOMIC_RELAXED, __HIP_MEMORY_SCOPE_AGENT);
      }
      __syncthreads();  // vmcnt(0) drain: publish at IF$ before arrive
      if (tid == 0)
        __hip_atomic_store(&flags[bid * FLAG_LINE_U32], (u32)(t + 2),
                           __ATOMIC_RELAXED, __HIP_MEMORY_SCOPE_AGENT);
    }
    // ---- out store LAST, sc1 write-through (no RFO, no 4-XCD line
    // ping-pong), AFTER the arrive so its completion is off the chain.
    if (tid < 256)
      __hip_atomic_store(&out[((size_t)t * BATCH + pb) * HDIM + bid * NJ + pj],
                         h_reg, __ATOMIC_RELAXED, __HIP_MEMORY_SCOPE_AGENT);
  }
}

extern "C" void kernel_launch(void* const* d_in, const int* in_sizes, int n_in,
                              void* d_out, int out_size, void* d_ws, size_t ws_size,
                              hipStream_t stream) {
  (void)in_sizes; (void)n_in; (void)out_size; (void)ws_size;
  const float* x = (const float*)d_in[0];
  const float* h0 = (const float*)d_in[1];
  const float* c0 = (const float*)d_in[2];
  const float* W = (const float*)d_in[3];
  const float* bias = (const float*)d_in[4];
  const int* L = (const int*)d_in[5];
  float* out = (float*)d_out;

  char* ws = (char*)d_ws;
  u32* flags = (u32*)ws;
  u16* xbf = (u16*)(ws + X_OFF);
  u16* hbuf = (u16*)(ws + H_OFF);

  hipFuncSetAttribute(reinterpret_cast<const void*>(lstm_persistent),
                      hipFuncAttributeMaxDynamicSharedMemorySize, 160 * 1024);
  hipMemsetAsync(ws, 0, 32768, stream);  // zero arrive flags + go lines
  hipLaunchKernelGGL(lstm_persistent, dim3(NBLK), dim3(THREADS), LDS_BYTES,
                     stream, x, h0, c0, W, bias, L, out, xbf, hbuf, flags);
}